// Round 5
// baseline (12270.747 us; speedup 1.0000x reference)
//
#include <hip/hip_runtime.h>
#include <hip/hip_bf16.h>

// ---------------- model constants ----------------
#define TSEQ   4096
#define DIMM   1024
#define NHEADS 8
#define DH     128
#define NHASH  4
#define NBUCK  64            // buckets per hash round
#define NCHUNK 256           // NHASH * NBUCK chunks of 64 sorted positions
#define BSZ    2
#define NBH    16            // BSZ * NHEADS
#define FFD    4096

__device__ __forceinline__ float gelu_tanh(float x) {
    float x3 = x * x * x;
    float inner = 0.7978845608028654f * (x + 0.044715f * x3);
    return 0.5f * x * (1.0f + tanhf(inner));
}

// ---------------- init: X1 = X2 = x ----------------
__global__ void init_kernel(const float* __restrict__ x, float* __restrict__ X1,
                            float* __restrict__ X2, int n) {
    int i = blockIdx.x * blockDim.x + threadIdx.x;
    if (i < n) { float v = x[i]; X1[i] = v; X2[i] = v; }
}

__global__ void zero_kernel(float* __restrict__ p, int n) {
    int i = blockIdx.x * blockDim.x + threadIdx.x;
    if (i < n) p[i] = 0.f;
}

// ---------------- layernorm (fp32): one 256-thread block per 1024-row ----------------
__global__ __launch_bounds__(256) void ln_kernel(const float* __restrict__ in,
                                                 const float* __restrict__ g,
                                                 const float* __restrict__ bb,
                                                 float* __restrict__ out) {
    int row = blockIdx.x;
    int tid = threadIdx.x;
    const float* xr = in + (size_t)row * DIMM;
    float v[4];
    float s = 0.f, sq = 0.f;
    #pragma unroll
    for (int k = 0; k < 4; k++) { float t = xr[tid + 256 * k]; v[k] = t; s += t; sq += t * t; }
    __shared__ float rs[256], rq[256];
    rs[tid] = s; rq[tid] = sq; __syncthreads();
    for (int off = 128; off > 0; off >>= 1) {
        if (tid < off) { rs[tid] += rs[tid + off]; rq[tid] += rq[tid + off]; }
        __syncthreads();
    }
    float mu  = rs[0] * (1.f / DIMM);
    float var = rq[0] * (1.f / DIMM) - mu * mu;
    float rstd = rsqrtf(var + 1e-5f);
    float* orow = out + (size_t)row * DIMM;
    #pragma unroll
    for (int k = 0; k < 4; k++) {
        int c = tid + 256 * k;
        orow[c] = (v[k] - mu) * rstd * g[c] + bb[c];
    }
}

// ---------------- fp32 tiled GEMM: C = A(MxK) @ B(KxN) [+bias][gelu][+resid] ----------------
// flags: 1=bias, 2=gelu (after bias), 4=residual add
#define GBM 64
#define GBN 64
#define GBK 32
__global__ __launch_bounds__(256) void gemm_kernel(const float* __restrict__ A,
                                                   const float* __restrict__ Bw,
                                                   const float* __restrict__ bias,
                                                   const float* __restrict__ resid,
                                                   float* __restrict__ C,
                                                   int M, int N, int K, int flags) {
    __shared__ float sA[GBK][GBM + 1];
    __shared__ float sB[GBK][GBN + 1];
    int tid = threadIdx.x;
    int tx = tid & 15, ty = tid >> 4;
    int n0 = blockIdx.x * GBN;
    int m0 = blockIdx.y * GBM;
    float acc[4][4] = {};
    for (int k0 = 0; k0 < K; k0 += GBK) {
        #pragma unroll
        for (int q = 0; q < 8; q++) {
            int idx = q * 256 + tid;
            int m = idx >> 5, kk = idx & 31;               // A tile 64x32
            sA[kk][m] = A[(size_t)(m0 + m) * K + k0 + kk];
            int n = idx & 63, kk2 = idx >> 6;              // B tile 32x64
            sB[kk2][n] = Bw[(size_t)(k0 + kk2) * N + n0 + n];
        }
        __syncthreads();
        #pragma unroll
        for (int kk = 0; kk < GBK; kk++) {
            float a[4], b[4];
            #pragma unroll
            for (int ri = 0; ri < 4; ri++) a[ri] = sA[kk][ty * 4 + ri];
            #pragma unroll
            for (int ci = 0; ci < 4; ci++) b[ci] = sB[kk][tx * 4 + ci];
            #pragma unroll
            for (int ri = 0; ri < 4; ri++)
                #pragma unroll
                for (int ci = 0; ci < 4; ci++)
                    acc[ri][ci] += a[ri] * b[ci];
        }
        __syncthreads();
    }
    #pragma unroll
    for (int ri = 0; ri < 4; ri++) {
        int row = m0 + ty * 4 + ri;
        #pragma unroll
        for (int ci = 0; ci < 4; ci++) {
            int col = n0 + tx * 4 + ci;
            float v = acc[ri][ci];
            if (flags & 1) v += bias[col];
            if (flags & 2) v = gelu_tanh(v);
            if (flags & 4) v += resid[(size_t)row * N + col];
            C[(size_t)row * N + col] = v;
        }
    }
}

// ---------------- fp64 bucketing: LN -> qk projection -> rotation -> argmax ----------------
// The argmax is the only discontinuous op in the model; compute its whole input
// chain in fp64 (exact on fp32 loads) to match a high-precision reference.
__global__ __launch_bounds__(128) void bucket_kernel(const float* __restrict__ Xsrc,
                                                     const float* __restrict__ g,
                                                     const float* __restrict__ bb,
                                                     const float* __restrict__ Wqk,
                                                     const float* __restrict__ rot,
                                                     int* __restrict__ bucket) {
    int t = blockIdx.x, bh = blockIdx.y;
    int b = bh >> 3, head = bh & 7;
    int tid = threadIdx.x;
    __shared__ double h64[DIMM];     // 8 KB
    __shared__ double red[128];
    __shared__ double qk64[DH];
    __shared__ double rots[128];
    const float* xr = Xsrc + (size_t)(b * TSEQ + t) * DIMM;
    double s = 0.0, sq = 0.0;
    for (int k = tid; k < DIMM; k += 128) {
        double v = (double)xr[k];
        h64[k] = v; s += v; sq += v * v;
    }
    red[tid] = s; __syncthreads();
    for (int off = 64; off > 0; off >>= 1) { if (tid < off) red[tid] += red[tid + off]; __syncthreads(); }
    double mu = red[0] * (1.0 / DIMM);
    __syncthreads();
    red[tid] = sq; __syncthreads();
    for (int off = 64; off > 0; off >>= 1) { if (tid < off) red[tid] += red[tid + off]; __syncthreads(); }
    double var = red[0] * (1.0 / DIMM) - mu * mu;
    double rstd = 1.0 / sqrt(var + 1e-5);
    __syncthreads();
    for (int k = tid; k < DIMM; k += 128)
        h64[k] = (h64[k] - mu) * rstd * (double)g[k] + (double)bb[k];
    __syncthreads();
    // qk64[tid] = sum_k h64[k] * Wqk[k][head*DH + tid]
    double qd = 0.0;
    int coff = head * DH + tid;
    for (int k = 0; k < DIMM; k++)
        qd += h64[k] * (double)Wqk[(size_t)k * DIMM + coff];
    qk64[tid] = qd;
    __syncthreads();
    // rotated[tid] = sum_d qk64[d] * rot[d][tid]   (tid = h*32 + r)
    double rv = 0.0;
    for (int d = 0; d < DH; d++)
        rv += qk64[d] * (double)rot[d * 128 + tid];
    rots[tid] = rv;
    __syncthreads();
    if (tid < 4) {
        int h = tid;
        double best = -1e300; int bi = 0;
        for (int rr = 0; rr < 64; rr++) {   // first-max wins, matches argmax
            double v = (rr < 32) ? rots[h * 32 + rr] : -rots[h * 32 + rr - 32];
            if (v > best) { best = v; bi = rr; }
        }
        bucket[(size_t)(bh * NHASH + h) * TSEQ + t] = bi;
    }
}

// ---------------- stable counting sort per (bh, hash round) ----------------
__global__ __launch_bounds__(64) void sort_kernel(const int* __restrict__ bucket,
                                                  int* __restrict__ st) {
    int h = blockIdx.x, bh = blockIdx.y;
    int tid = threadIdx.x;   // one thread per bucket bin
    __shared__ int sbuck[TSEQ];
    __shared__ int cnt[NBUCK];
    cnt[tid] = 0;
    __syncthreads();
    const int* brow = bucket + (size_t)(bh * NHASH + h) * TSEQ;
    for (int t = tid; t < TSEQ; t += 64) {
        int bu = brow[t];
        sbuck[t] = bu;
        atomicAdd(&cnt[bu], 1);
    }
    __syncthreads();
    if (tid == 0) {
        int run = 0;
        for (int i = 0; i < NBUCK; i++) { int c = cnt[i]; cnt[i] = run; run += c; }
    }
    __syncthreads();
    int off = cnt[tid];
    int* strow = st + (size_t)bh * (NHASH * TSEQ) + h * TSEQ;
    for (int t = 0; t < TSEQ; t++) {        // t-ascending => stable
        if (sbuck[t] == tid) strow[off++] = t;
    }
}

// ---------------- per-token key inverse norms ----------------
__global__ __launch_bounds__(256) void norm_kernel(const float* __restrict__ QK,
                                                   float* __restrict__ invn) {
    int bh = blockIdx.y;
    int b = bh >> 3, head = bh & 7;
    int wave = threadIdx.x >> 6, lane = threadIdx.x & 63;
    int t = blockIdx.x * 4 + wave;
    const float* row = QK + (size_t)(b * TSEQ + t) * DIMM + head * DH;
    float v0 = row[lane], v1 = row[lane + 64];
    float s = v0 * v0 + v1 * v1;
    #pragma unroll
    for (int off = 32; off > 0; off >>= 1) s += __shfl_xor(s, off, 64);
    if (lane == 0) invn[bh * TSEQ + t] = rsqrtf(s + 1e-12f);
}

// ---------------- chunked LSH attention, two-pass ----------------
// MODE 0: per-round lse -> OutP(=Lg).  MODE 1: recompute dots, cross-round
// softmax weight from LgIn, atomicAdd w*(P@V) into OutP(=AO).
template<int MODE>
__global__ __launch_bounds__(256) void attn_kernel(const float* __restrict__ QK,
                                                   const float* __restrict__ V,
                                                   const float* __restrict__ invn,
                                                   const int* __restrict__ st,
                                                   const float* __restrict__ LgIn,
                                                   float* __restrict__ OutP) {
    int c  = blockIdx.x;          // 0..255
    int bh = blockIdx.y;          // 0..15
    int b = bh >> 3, head = bh & 7;
    const float* QKb = QK + (size_t)b * TSEQ * DIMM + head * DH;
    const float* Vb  = V  + (size_t)b * TSEQ * DIMM + head * DH;
    const int* stb = st + (size_t)bh * (NHASH * TSEQ);
    int prev = (c + NCHUNK - 1) & (NCHUNK - 1);
    int round = c >> 6;
    int tid = threadIdx.x;
    int tx = tid & 15, ty = tid >> 4;

    __shared__ float sdots[64][129];     // dots then scaled probs
    __shared__ float sstage[3264];       // sQ[64][17] + sK[128][17]; reused as sV[16][129]
    __shared__ int   sbt[64];
    __shared__ int   sbkt[128];
    __shared__ float sinv[128];

    if (tid < 64) sbt[tid] = stb[c * 64 + tid];
    if (tid < 128) {
        int j = tid;
        int p = (j < 64) ? (c * 64 + j) : (prev * 64 + j - 64);
        int tk = stb[p];
        sbkt[j] = tk;
        sinv[j] = invn[bh * TSEQ + tk];
    }
    __syncthreads();

    // ---- dots = bq @ bk^T : rows i = ty*4+ri, cols j = tx + 16*ci ----
    float acc[4][8] = {};
    float* sQ = sstage;            // [64][17]
    float* sK = sstage + 64 * 17;  // [128][17]
    for (int d0 = 0; d0 < DH; d0 += 16) {
        #pragma unroll
        for (int q = 0; q < 4; q++) {
            int idx = q * 256 + tid;
            int i = idx >> 4, dd = idx & 15;
            sQ[i * 17 + dd] = QKb[(size_t)sbt[i] * DIMM + d0 + dd];
        }
        #pragma unroll
        for (int q = 0; q < 8; q++) {
            int idx = q * 256 + tid;
            int j = idx >> 4, dd = idx & 15;
            sK[j * 17 + dd] = QKb[(size_t)sbkt[j] * DIMM + d0 + dd];
        }
        __syncthreads();
        #pragma unroll
        for (int dd = 0; dd < 16; dd++) {
            float a[4], bv[8];
            #pragma unroll
            for (int ri = 0; ri < 4; ri++) a[ri] = sQ[(ty * 4 + ri) * 17 + dd];
            #pragma unroll
            for (int ci = 0; ci < 8; ci++) bv[ci] = sK[(tx + 16 * ci) * 17 + dd];
            #pragma unroll
            for (int ri = 0; ri < 4; ri++)
                #pragma unroll
                for (int ci = 0; ci < 8; ci++)
                    acc[ri][ci] += a[ri] * bv[ci];
        }
        __syncthreads();
    }
    const float scale = 0.08838834764831845f;  // 128^-0.5
    #pragma unroll
    for (int ri = 0; ri < 4; ri++) {
        int i = ty * 4 + ri;
        #pragma unroll
        for (int ci = 0; ci < 8; ci++) {
            int j = tx + 16 * ci;
            float v = acc[ri][ci] * sinv[j] * scale;
            if (sbt[i] == sbkt[j]) v -= 1e5f;   // self-attention mask
            sdots[i][j] = v;
        }
    }
    __syncthreads();

    // ---- row softmax (threads 0..63, one row each) ----
    if (tid < 64) {
        float m = -3.402823466e38f;
        for (int j = 0; j < 128; j++) m = fmaxf(m, sdots[tid][j]);
        float s = 0.f;
        for (int j = 0; j < 128; j++) s += expf(sdots[tid][j] - m);
        if (MODE == 0) {
            OutP[(size_t)(bh * NHASH + round) * TSEQ + sbt[tid]] = m + logf(s);
        } else {
            float l[NHASH];
            float m4 = -3.402823466e38f;
            #pragma unroll
            for (int h = 0; h < NHASH; h++) {
                l[h] = LgIn[(size_t)(bh * NHASH + h) * TSEQ + sbt[tid]];
                m4 = fmaxf(m4, l[h]);
            }
            float wsum = 0.f;
            #pragma unroll
            for (int h = 0; h < NHASH; h++) wsum += expf(l[h] - m4);
            float w = expf(l[round] - m4) / wsum;
            float sc = w / s;
            for (int j = 0; j < 128; j++) sdots[tid][j] = expf(sdots[tid][j] - m) * sc;
        }
    }
    if (MODE == 0) return;
    __syncthreads();

    // ---- out += (w*probs) @ V : rows i = ty*4+ri, cols d = tx + 16*ci ----
    float acc2[4][8] = {};
    float* sV = sstage;            // [16][129]
    for (int j0 = 0; j0 < 128; j0 += 16) {
        #pragma unroll
        for (int q = 0; q < 8; q++) {
            int idx = q * 256 + tid;
            int jj = idx >> 7, d = idx & 127;
            sV[jj * 129 + d] = Vb[(size_t)sbkt[j0 + jj] * DIMM + d];
        }
        __syncthreads();
        #pragma unroll
        for (int jj = 0; jj < 16; jj++) {
            float a[4], vv[8];
            #pragma unroll
            for (int ri = 0; ri < 4; ri++) a[ri] = sdots[ty * 4 + ri][j0 + jj];
            #pragma unroll
            for (int ci = 0; ci < 8; ci++) vv[ci] = sV[jj * 129 + tx + 16 * ci];
            #pragma unroll
            for (int ri = 0; ri < 4; ri++)
                #pragma unroll
                for (int ci = 0; ci < 8; ci++)
                    acc2[ri][ci] += a[ri] * vv[ci];
        }
        __syncthreads();
    }
    #pragma unroll
    for (int ri = 0; ri < 4; ri++) {
        int i = ty * 4 + ri;
        float* orow = OutP + (size_t)(b * TSEQ + sbt[i]) * DIMM + head * DH;
        #pragma unroll
        for (int ci = 0; ci < 8; ci++)
            atomicAdd(&orow[tx + 16 * ci], acc2[ri][ci]);
    }
}

// ---------------- final: out = 0.5*(X1+X2), fp32 (reference output dtype) ----------------
__global__ void final_kernel(const float* __restrict__ X1, const float* __restrict__ X2,
                             float* __restrict__ out, int n) {
    int i = blockIdx.x * blockDim.x + threadIdx.x;
    if (i < n) out[i] = 0.5f * (X1[i] + X2[i]);
}

extern "C" void kernel_launch(void* const* d_in, const int* in_sizes, int n_in,
                              void* d_out, int out_size, void* d_ws, size_t ws_size,
                              hipStream_t stream) {
    (void)in_sizes; (void)n_in; (void)out_size; (void)ws_size;
    const float* x    = (const float*)d_in[0];
    // d_in[1] = mask (all ones, unused by reference)
    const float* ln1g = (const float*)d_in[2];
    const float* ln1b = (const float*)d_in[3];
    const float* Wqk  = (const float*)d_in[4];
    const float* Wv   = (const float*)d_in[5];
    const float* Wo   = (const float*)d_in[6];
    const float* bo   = (const float*)d_in[7];
    const float* ln2g = (const float*)d_in[8];
    const float* ln2b = (const float*)d_in[9];
    const float* W1   = (const float*)d_in[10];
    const float* b1   = (const float*)d_in[11];
    const float* W2   = (const float*)d_in[12];
    const float* b2   = (const float*)d_in[13];
    const float* rot  = (const float*)d_in[14];
    float* out = (float*)d_out;

    // ---- workspace layout (~163.3 MB) ----
    char* ws = (char*)d_ws;
    const size_t SZ = (size_t)BSZ * TSEQ * DIMM * sizeof(float);   // 32 MB
    float* X1 = (float*)(ws + 0 * SZ);
    float* X2 = (float*)(ws + 1 * SZ);
    float* H  = (float*)(ws + 2 * SZ);          // LN out; later AO (attention out)
    float* QK = (float*)(ws + 3 * SZ);
    float* V  = (float*)(ws + 4 * SZ);
    float* G  = QK;                             // FF hidden (4096x4096 fp32 = 64MB) over QK|V
    char* p = ws + 5 * SZ;
    float* Lg   = (float*)p; p += (size_t)NBH * NHASH * TSEQ * sizeof(float);   // 1 MB
    float* invn = (float*)p; p += (size_t)NBH * TSEQ * sizeof(float);           // 256 KB
    int*   bucket = (int*)p; p += (size_t)NBH * NHASH * TSEQ * sizeof(int);     // 1 MB
    int*   st     = (int*)p; p += (size_t)NBH * NHASH * TSEQ * sizeof(int);     // 1 MB

    const int MROWS = BSZ * TSEQ;    // 8192
    const int NELEM = MROWS * DIMM;  // 8388608

    init_kernel<<<(NELEM + 255) / 256, 256, 0, stream>>>(x, X1, X2, NELEM);

    for (int l = 0; l < 2; l++) {
        const float* wqk = Wqk + (size_t)l * DIMM * DIMM;
        const float* wv  = Wv  + (size_t)l * DIMM * DIMM;
        const float* wo  = Wo  + (size_t)l * DIMM * DIMM;
        const float* w1  = W1  + (size_t)l * DIMM * FFD;
        const float* w2  = W2  + (size_t)l * FFD * DIMM;
        const float* rotl = rot + (size_t)l * DH * NHASH * (NBUCK / 2);

        // a = LSHAttn(LN(x2)); y1 = x1 + a
        ln_kernel<<<MROWS, 256, 0, stream>>>(X2, ln1g + l * DIMM, ln1b + l * DIMM, H);
        gemm_kernel<<<dim3(DIMM / GBN, MROWS / GBM), 256, 0, stream>>>(
            H, wqk, nullptr, nullptr, QK, MROWS, DIMM, DIMM, 0);
        gemm_kernel<<<dim3(DIMM / GBN, MROWS / GBM), 256, 0, stream>>>(
            H, wv, nullptr, nullptr, V, MROWS, DIMM, DIMM, 0);
        bucket_kernel<<<dim3(TSEQ, NBH), 128, 0, stream>>>(
            X2, ln1g + l * DIMM, ln1b + l * DIMM, wqk, rotl, bucket);
        sort_kernel<<<dim3(NHASH, NBH), 64, 0, stream>>>(bucket, st);
        norm_kernel<<<dim3(TSEQ / 4, NBH), 256, 0, stream>>>(QK, invn);
        attn_kernel<0><<<dim3(NCHUNK, NBH), 256, 0, stream>>>(QK, V, invn, st, nullptr, Lg);
        zero_kernel<<<(NELEM + 255) / 256, 256, 0, stream>>>(H, NELEM);   // H becomes AO
        attn_kernel<1><<<dim3(NCHUNK, NBH), 256, 0, stream>>>(QK, V, invn, st, Lg, H);
        gemm_kernel<<<dim3(DIMM / GBN, MROWS / GBM), 256, 0, stream>>>(
            H, wo, bo + l * DIMM, X1, X1, MROWS, DIMM, DIMM, 1 | 4);  // X1 += AO@Wo + bo

        // y2 = x2 + FF(LN(y1)); FF in 2 row-chunks so G (64MB) fits over QK|V
        ln_kernel<<<MROWS, 256, 0, stream>>>(X1, ln2g + l * DIMM, ln2b + l * DIMM, H);
        for (int ch = 0; ch < 2; ch++) {
            const int CR = MROWS / 2;        // 4096 rows per chunk
            float* Hc  = H  + (size_t)ch * CR * DIMM;
            float* X2c = X2 + (size_t)ch * CR * DIMM;
            gemm_kernel<<<dim3(FFD / GBN, CR / GBM), 256, 0, stream>>>(
                Hc, w1, b1 + l * FFD, nullptr, G, CR, FFD, DIMM, 1 | 2);    // G = gelu(Hc@W1+b1)
            gemm_kernel<<<dim3(DIMM / GBN, CR / GBM), 256, 0, stream>>>(
                G, w2, b2 + l * DIMM, X2c, X2c, CR, DIMM, FFD, 1 | 4);      // X2c += G@W2+b2
        }
    }

    final_kernel<<<(NELEM + 255) / 256, 256, 0, stream>>>(X1, X2, out, NELEM);
}

// Round 6
// 4405.066 us; speedup vs baseline: 2.7856x; 2.7856x over previous
//
#include <hip/hip_runtime.h>
#include <hip/hip_bf16.h>

// ---------------- model constants ----------------
#define TSEQ   4096
#define DIMM   1024
#define NHEADS 8
#define DH     128
#define NHASH  4
#define NBUCK  64
#define NCHUNK 256           // NHASH * NBUCK chunks of 64 sorted positions
#define BSZ    2
#define NBH    16            // BSZ * NHEADS
#define FFD    4096

typedef __attribute__((ext_vector_type(4))) float f32x4;
typedef __attribute__((ext_vector_type(8))) short s16x8;

__device__ __forceinline__ unsigned short f2bf(float f) {
    union { float f; unsigned int u; } x; x.f = f;
    unsigned int r = x.u + 0x7FFFu + ((x.u >> 16) & 1u);   // RNE
    return (unsigned short)(r >> 16);
}

__device__ __forceinline__ void async16(const void* g, void* l) {
    __builtin_amdgcn_global_load_lds(
        (const __attribute__((address_space(1))) unsigned int*)g,
        (__attribute__((address_space(3))) unsigned int*)l, 16, 0, 0);
}

__device__ __forceinline__ float gelu_tanh(float x) {
    float x3 = x * x * x;
    float inner = 0.7978845608028654f * (x + 0.044715f * x3);
    return 0.5f * x * (1.0f + tanhf(inner));
}

// ---------------- init / zero / converts ----------------
__global__ void init_kernel(const float* __restrict__ x, float* __restrict__ X1,
                            float* __restrict__ X2, int n) {
    int i = blockIdx.x * blockDim.x + threadIdx.x;
    if (i < n) { float v = x[i]; X1[i] = v; X2[i] = v; }
}

__global__ void zero_kernel(float* __restrict__ p, int n) {
    int i = blockIdx.x * blockDim.x + threadIdx.x;
    if (i < n) p[i] = 0.f;
}

__global__ void c2b_kernel(const float* __restrict__ in, unsigned short* __restrict__ out, int n) {
    int i = blockIdx.x * blockDim.x + threadIdx.x;
    if (i < n) out[i] = f2bf(in[i]);
}

// convert + transpose: in[K x N] fp32 -> out[N x K] bf16
__global__ __launch_bounds__(256) void convT_kernel(const float* __restrict__ in,
                                                    unsigned short* __restrict__ out,
                                                    int K, int N) {
    __shared__ float tile[32][33];
    int n0 = blockIdx.x * 32, k0 = blockIdx.y * 32;
    int tx = threadIdx.x & 31, ty = threadIdx.x >> 5;
    #pragma unroll
    for (int r = 0; r < 4; r++)
        tile[ty + r * 8][tx] = in[(size_t)(k0 + ty + r * 8) * N + n0 + tx];
    __syncthreads();
    #pragma unroll
    for (int r = 0; r < 4; r++)
        out[(size_t)(n0 + ty + r * 8) * K + k0 + tx] = f2bf(tile[tx][ty + r * 8]);
}

// ---------------- layernorm -> bf16 out ----------------
__global__ __launch_bounds__(256) void ln_bf16_kernel(const float* __restrict__ in,
                                                      const float* __restrict__ g,
                                                      const float* __restrict__ bb,
                                                      unsigned short* __restrict__ out) {
    int row = blockIdx.x;
    int tid = threadIdx.x;
    const float* xr = in + (size_t)row * DIMM;
    float v[4];
    float s = 0.f, sq = 0.f;
    #pragma unroll
    for (int k = 0; k < 4; k++) { float t = xr[tid + 256 * k]; v[k] = t; s += t; sq += t * t; }
    __shared__ float rs[256], rq[256];
    rs[tid] = s; rq[tid] = sq; __syncthreads();
    for (int off = 128; off > 0; off >>= 1) {
        if (tid < off) { rs[tid] += rs[tid + off]; rq[tid] += rq[tid + off]; }
        __syncthreads();
    }
    float mu  = rs[0] * (1.f / DIMM);
    float var = rq[0] * (1.f / DIMM) - mu * mu;
    float rstd = rsqrtf(var + 1e-5f);
    unsigned short* orow = out + (size_t)row * DIMM;
    #pragma unroll
    for (int k = 0; k < 4; k++) {
        int c = tid + 256 * k;
        orow[c] = f2bf((v[k] - mu) * rstd * g[c] + bb[c]);
    }
}

// ---------------- bf16 MFMA GEMM: C = A @ B [+bias][gelu][+resid] ----------------
// A [M x K] bf16 row-major; Bt [N x K] bf16 (B transposed). 128x128x32 tile,
// 256 threads = 4 waves, each wave 64x64 via 4x4 of 16x16x32 MFMAs.
template<int OUT_BF16>
__global__ __launch_bounds__(256) void mgemm_kernel(const unsigned short* __restrict__ A,
                                                    const unsigned short* __restrict__ Bt,
                                                    const float* __restrict__ bias,
                                                    const float* __restrict__ resid,
                                                    void* __restrict__ Cv,
                                                    int M, int N, int K, int flags) {
    __shared__ __align__(16) unsigned short sA[128 * 32];
    __shared__ __align__(16) unsigned short sB[128 * 32];
    int tid = threadIdx.x;
    int wave = tid >> 6, lane = tid & 63;
    int n0 = blockIdx.x * 128, m0 = blockIdx.y * 128;
    int wr = (wave >> 1) * 64, wc = (wave & 1) * 64;
    f32x4 acc[4][4] = {};
    int c1 = tid, c2 = tid + 256;                     // chunk = (row<<2)|kq
    const unsigned short* gA1 = A + (size_t)(m0 + (c1 >> 2)) * K + (c1 & 3) * 8;
    const unsigned short* gA2 = A + (size_t)(m0 + (c2 >> 2)) * K + (c2 & 3) * 8;
    const unsigned short* gB1 = Bt + (size_t)(n0 + (c1 >> 2)) * K + (c1 & 3) * 8;
    const unsigned short* gB2 = Bt + (size_t)(n0 + (c2 >> 2)) * K + (c2 & 3) * 8;
    unsigned short* lA1 = sA + wave * 512;            // wave-uniform LDS bases
    unsigned short* lA2 = sA + 2048 + wave * 512;
    unsigned short* lB1 = sB + wave * 512;
    unsigned short* lB2 = sB + 2048 + wave * 512;
    int qk8 = (lane >> 4) * 8;
    int r16 = lane & 15;
    for (int k0 = 0; k0 < K; k0 += 32) {
        __syncthreads();                 // prev iter's LDS reads done
        async16(gA1 + k0, lA1);
        async16(gA2 + k0, lA2);
        async16(gB1 + k0, lB1);
        async16(gB2 + k0, lB2);
        __syncthreads();                 // vmcnt(0) drain -> tiles ready
        s16x8 af[4], bf[4];
        #pragma unroll
        for (int i = 0; i < 4; i++) {
            af[i] = *(const s16x8*)&sA[(wr + i * 16 + r16) * 32 + qk8];
            bf[i] = *(const s16x8*)&sB[(wc + i * 16 + r16) * 32 + qk8];
        }
        #pragma unroll
        for (int mi = 0; mi < 4; mi++)
            #pragma unroll
            for (int ni = 0; ni < 4; ni++)
                acc[mi][ni] = __builtin_amdgcn_mfma_f32_16x16x32_bf16(af[mi], bf[ni], acc[mi][ni], 0, 0, 0);
    }
    // epilogue: C row = (lane>>4)*4+reg, col = lane&15 within each 16x16
    #pragma unroll
    for (int mi = 0; mi < 4; mi++) {
        #pragma unroll
        for (int r = 0; r < 4; r++) {
            int row = m0 + wr + mi * 16 + (lane >> 4) * 4 + r;
            #pragma unroll
            for (int ni = 0; ni < 4; ni++) {
                int col = n0 + wc + ni * 16 + (lane & 15);
                float v = acc[mi][ni][r];
                if (flags & 1) v += bias[col];
                if (flags & 2) v = gelu_tanh(v);
                if (flags & 4) v += resid[(size_t)row * N + col];
                if (OUT_BF16) ((unsigned short*)Cv)[(size_t)row * N + col] = f2bf(v);
                else          ((float*)Cv)[(size_t)row * N + col] = v;
            }
        }
    }
}

// ---------------- fp64 bucketing v2: 2 tokens/block, all 8 heads, ILP-8 ----------------
// Same fp64 op order per output as the verified r5 kernel (serial k, serial d).
__global__ __launch_bounds__(256) void bucket2_kernel(const float* __restrict__ Xsrc,
                                                      const float* __restrict__ g,
                                                      const float* __restrict__ bb,
                                                      const float* __restrict__ Wqk,
                                                      const float* __restrict__ rot,
                                                      int* __restrict__ bucket) {
    int b = blockIdx.y;
    int t0 = blockIdx.x * 2;
    int tid = threadIdx.x;
    __shared__ double h64[2][DIMM];      // 16 KB; reused as rots after qk
    __shared__ double qk64[2][DIMM];     // 16 KB
    __shared__ double red[256];

    #pragma unroll
    for (int tt = 0; tt < 2; tt++) {
        const float* xr = Xsrc + (size_t)(b * TSEQ + t0 + tt) * DIMM;
        double s = 0.0, sq = 0.0;
        for (int k = tid; k < DIMM; k += 256) {
            double v = (double)xr[k];
            h64[tt][k] = v; s += v; sq += v * v;
        }
        red[tid] = s; __syncthreads();
        for (int off = 128; off > 0; off >>= 1) { if (tid < off) red[tid] += red[tid + off]; __syncthreads(); }
        double mu = red[0] * (1.0 / DIMM);
        __syncthreads();
        red[tid] = sq; __syncthreads();
        for (int off = 128; off > 0; off >>= 1) { if (tid < off) red[tid] += red[tid + off]; __syncthreads(); }
        double var = red[0] * (1.0 / DIMM) - mu * mu;
        double rstd = 1.0 / sqrt(var + 1e-5);
        __syncthreads();
        for (int k = tid; k < DIMM; k += 256)
            h64[tt][k] = (h64[tt][k] - mu) * rstd * (double)g[k] + (double)bb[k];
    }
    __syncthreads();

    // qk = LN64 @ Wqk : 8 independent fp64 accumulators (2 tokens x 4 cols)
    double a00 = 0, a01 = 0, a02 = 0, a03 = 0, a10 = 0, a11 = 0, a12 = 0, a13 = 0;
    #pragma unroll 4
    for (int k = 0; k < DIMM; k++) {
        const float* wr_ = Wqk + (size_t)k * DIMM + tid;
        double w0 = (double)wr_[0], w1 = (double)wr_[256];
        double w2 = (double)wr_[512], w3 = (double)wr_[768];
        double h0 = h64[0][k], h1 = h64[1][k];
        a00 += h0 * w0; a01 += h0 * w1; a02 += h0 * w2; a03 += h0 * w3;
        a10 += h1 * w0; a11 += h1 * w1; a12 += h1 * w2; a13 += h1 * w3;
    }
    qk64[0][tid] = a00; qk64[0][tid + 256] = a01; qk64[0][tid + 512] = a02; qk64[0][tid + 768] = a03;
    qk64[1][tid] = a10; qk64[1][tid + 256] = a11; qk64[1][tid + 512] = a12; qk64[1][tid + 768] = a13;
    __syncthreads();

    // rotation: rotated[j] = sum_d qk64[head(j)*128+d] * rot[d*128 + (j&127)]
    double* rots = &h64[0][0];           // alias (h64 dead)
    int hr = tid & 127;
    int hbase = tid >> 7;
    double r0[4] = {}, r1[4] = {};
    for (int d = 0; d < 128; d++) {
        double rv = (double)rot[d * 128 + hr];
        #pragma unroll
        for (int s = 0; s < 4; s++) {
            int head = hbase + s * 2;
            r0[s] += qk64[0][head * 128 + d] * rv;   // LDS broadcast per wave
            r1[s] += qk64[1][head * 128 + d] * rv;
        }
    }
    #pragma unroll
    for (int s = 0; s < 4; s++) {
        rots[0 * DIMM + tid + s * 256] = r0[s];
        rots[1 * DIMM + tid + s * 256] = r1[s];
    }
    __syncthreads();
    if (tid < 64) {
        int tt = tid >> 5, idx = tid & 31;
        int head = idx >> 2, h = idx & 3;
        const double* rr = rots + tt * DIMM + head * 128 + h * 32;
        double best = -1e300; int bi = 0;
        for (int j = 0; j < 64; j++) {       // first-max wins, matches argmax
            double v = (j < 32) ? rr[j] : -rr[j - 32];
            if (v > best) { best = v; bi = j; }
        }
        bucket[(size_t)((b * 8 + head) * NHASH + h) * TSEQ + (t0 + tt)] = bi;
    }
}

// ---------------- stable counting sort per (bh, hash round) ----------------
__global__ __launch_bounds__(64) void sort_kernel(const int* __restrict__ bucket,
                                                  int* __restrict__ st) {
    int h = blockIdx.x, bh = blockIdx.y;
    int tid = threadIdx.x;
    __shared__ int sbuck[TSEQ];
    __shared__ int cnt[NBUCK];
    cnt[tid] = 0;
    __syncthreads();
    const int* brow = bucket + (size_t)(bh * NHASH + h) * TSEQ;
    for (int t = tid; t < TSEQ; t += 64) {
        int bu = brow[t];
        sbuck[t] = bu;
        atomicAdd(&cnt[bu], 1);
    }
    __syncthreads();
    if (tid == 0) {
        int run = 0;
        for (int i = 0; i < NBUCK; i++) { int c = cnt[i]; cnt[i] = run; run += c; }
    }
    __syncthreads();
    int off = cnt[tid];
    int* strow = st + (size_t)bh * (NHASH * TSEQ) + h * TSEQ;
    for (int t = 0; t < TSEQ; t++) {
        if (sbuck[t] == tid) strow[off++] = t;
    }
}

// ---------------- per-token key inverse norms ----------------
__global__ __launch_bounds__(256) void norm_kernel(const float* __restrict__ QK,
                                                   float* __restrict__ invn) {
    int bh = blockIdx.y;
    int b = bh >> 3, head = bh & 7;
    int wave = threadIdx.x >> 6, lane = threadIdx.x & 63;
    int t = blockIdx.x * 4 + wave;
    const float* row = QK + (size_t)(b * TSEQ + t) * DIMM + head * DH;
    float v0 = row[lane], v1 = row[lane + 64];
    float s = v0 * v0 + v1 * v1;
    #pragma unroll
    for (int off = 32; off > 0; off >>= 1) s += __shfl_xor(s, off, 64);
    if (lane == 0) invn[bh * TSEQ + t] = rsqrtf(s + 1e-12f);
}

// ---------------- chunked LSH attention, two-pass ----------------
template<int MODE>
__global__ __launch_bounds__(256) void attn_kernel(const float* __restrict__ QK,
                                                   const float* __restrict__ V,
                                                   const float* __restrict__ invn,
                                                   const int* __restrict__ st,
                                                   const float* __restrict__ LgIn,
                                                   float* __restrict__ OutP) {
    int c  = blockIdx.x;
    int bh = blockIdx.y;
    int b = bh >> 3, head = bh & 7;
    const float* QKb = QK + (size_t)b * TSEQ * DIMM + head * DH;
    const float* Vb  = V  + (size_t)b * TSEQ * DIMM + head * DH;
    const int* stb = st + (size_t)bh * (NHASH * TSEQ);
    int prev = (c + NCHUNK - 1) & (NCHUNK - 1);
    int round = c >> 6;
    int tid = threadIdx.x;
    int tx = tid & 15, ty = tid >> 4;

    __shared__ float sdots[64][129];
    __shared__ float sstage[3264];
    __shared__ int   sbt[64];
    __shared__ int   sbkt[128];
    __shared__ float sinv[128];

    if (tid < 64) sbt[tid] = stb[c * 64 + tid];
    if (tid < 128) {
        int j = tid;
        int p = (j < 64) ? (c * 64 + j) : (prev * 64 + j - 64);
        int tk = stb[p];
        sbkt[j] = tk;
        sinv[j] = invn[bh * TSEQ + tk];
    }
    __syncthreads();

    float acc[4][8] = {};
    float* sQ = sstage;
    float* sK = sstage + 64 * 17;
    for (int d0 = 0; d0 < DH; d0 += 16) {
        #pragma unroll
        for (int q = 0; q < 4; q++) {
            int idx = q * 256 + tid;
            int i = idx >> 4, dd = idx & 15;
            sQ[i * 17 + dd] = QKb[(size_t)sbt[i] * DIMM + d0 + dd];
        }
        #pragma unroll
        for (int q = 0; q < 8; q++) {
            int idx = q * 256 + tid;
            int j = idx >> 4, dd = idx & 15;
            sK[j * 17 + dd] = QKb[(size_t)sbkt[j] * DIMM + d0 + dd];
        }
        __syncthreads();
        #pragma unroll
        for (int dd = 0; dd < 16; dd++) {
            float a[4], bv[8];
            #pragma unroll
            for (int ri = 0; ri < 4; ri++) a[ri] = sQ[(ty * 4 + ri) * 17 + dd];
            #pragma unroll
            for (int ci = 0; ci < 8; ci++) bv[ci] = sK[(tx + 16 * ci) * 17 + dd];
            #pragma unroll
            for (int ri = 0; ri < 4; ri++)
                #pragma unroll
                for (int ci = 0; ci < 8; ci++)
                    acc[ri][ci] += a[ri] * bv[ci];
        }
        __syncthreads();
    }
    const float scale = 0.08838834764831845f;
    #pragma unroll
    for (int ri = 0; ri < 4; ri++) {
        int i = ty * 4 + ri;
        #pragma unroll
        for (int ci = 0; ci < 8; ci++) {
            int j = tx + 16 * ci;
            float v = acc[ri][ci] * sinv[j] * scale;
            if (sbt[i] == sbkt[j]) v -= 1e5f;
            sdots[i][j] = v;
        }
    }
    __syncthreads();

    if (tid < 64) {
        float m = -3.402823466e38f;
        for (int j = 0; j < 128; j++) m = fmaxf(m, sdots[tid][j]);
        float s = 0.f;
        for (int j = 0; j < 128; j++) s += expf(sdots[tid][j] - m);
        if (MODE == 0) {
            OutP[(size_t)(bh * NHASH + round) * TSEQ + sbt[tid]] = m + logf(s);
        } else {
            float l[NHASH];
            float m4 = -3.402823466e38f;
            #pragma unroll
            for (int h = 0; h < NHASH; h++) {
                l[h] = LgIn[(size_t)(bh * NHASH + h) * TSEQ + sbt[tid]];
                m4 = fmaxf(m4, l[h]);
            }
            float wsum = 0.f;
            #pragma unroll
            for (int h = 0; h < NHASH; h++) wsum += expf(l[h] - m4);
            float w = expf(l[round] - m4) / wsum;
            float sc = w / s;
            for (int j = 0; j < 128; j++) sdots[tid][j] = expf(sdots[tid][j] - m) * sc;
        }
    }
    if (MODE == 0) return;
    __syncthreads();

    float acc2[4][8] = {};
    float* sV = sstage;
    for (int j0 = 0; j0 < 128; j0 += 16) {
        #pragma unroll
        for (int q = 0; q < 8; q++) {
            int idx = q * 256 + tid;
            int jj = idx >> 7, d = idx & 127;
            sV[jj * 129 + d] = Vb[(size_t)sbkt[j0 + jj] * DIMM + d];
        }
        __syncthreads();
        #pragma unroll
        for (int jj = 0; jj < 16; jj++) {
            float a[4], vv[8];
            #pragma unroll
            for (int ri = 0; ri < 4; ri++) a[ri] = sdots[ty * 4 + ri][j0 + jj];
            #pragma unroll
            for (int ci = 0; ci < 8; ci++) vv[ci] = sV[jj * 129 + tx + 16 * ci];
            #pragma unroll
            for (int ri = 0; ri < 4; ri++)
                #pragma unroll
                for (int ci = 0; ci < 8; ci++)
                    acc2[ri][ci] += a[ri] * vv[ci];
        }
        __syncthreads();
    }
    #pragma unroll
    for (int ri = 0; ri < 4; ri++) {
        int i = ty * 4 + ri;
        float* orow = OutP + (size_t)(b * TSEQ + sbt[i]) * DIMM + head * DH;
        #pragma unroll
        for (int ci = 0; ci < 8; ci++)
            atomicAdd(&orow[tx + 16 * ci], acc2[ri][ci]);
    }
}

// ---------------- final: out = 0.5*(X1+X2), fp32 ----------------
__global__ void final_kernel(const float* __restrict__ X1, const float* __restrict__ X2,
                             float* __restrict__ out, int n) {
    int i = blockIdx.x * blockDim.x + threadIdx.x;
    if (i < n) out[i] = 0.5f * (X1[i] + X2[i]);
}

extern "C" void kernel_launch(void* const* d_in, const int* in_sizes, int n_in,
                              void* d_out, int out_size, void* d_ws, size_t ws_size,
                              hipStream_t stream) {
    (void)in_sizes; (void)n_in; (void)out_size; (void)ws_size;
    const float* x    = (const float*)d_in[0];
    const float* ln1g = (const float*)d_in[2];
    const float* ln1b = (const float*)d_in[3];
    const float* Wqk  = (const float*)d_in[4];
    const float* Wv   = (const float*)d_in[5];
    const float* Wo   = (const float*)d_in[6];
    const float* bo   = (const float*)d_in[7];
    const float* ln2g = (const float*)d_in[8];
    const float* ln2b = (const float*)d_in[9];
    const float* W1   = (const float*)d_in[10];
    const float* b1   = (const float*)d_in[11];
    const float* W2   = (const float*)d_in[12];
    const float* b2   = (const float*)d_in[13];
    const float* rot  = (const float*)d_in[14];
    float* out = (float*)d_out;

    // ---- workspace layout (163.3 MB, same known-good footprint) ----
    char* ws = (char*)d_ws;
    const size_t SZ  = (size_t)BSZ * TSEQ * DIMM * sizeof(float);   // 32 MB
    const size_t HSZ = SZ / 2;                                      // 16 MB
    float* X1 = (float*)(ws + 0 * SZ);
    float* X2 = (float*)(ws + 1 * SZ);
    // H region [2SZ,3SZ): Hb bf16 [0,16) + Wb bf16 [16,24) ; later AO fp32 (32MB)
    unsigned short* Hb  = (unsigned short*)(ws + 2 * SZ);
    unsigned short* Wb  = (unsigned short*)(ws + 2 * SZ + HSZ);
    float* AO = (float*)(ws + 2 * SZ);
    // QK region [3SZ,4SZ): QK fp32 ; later AOb bf16 [0,16) + Wob [16,18)
    float* QK = (float*)(ws + 3 * SZ);
    unsigned short* AOb = (unsigned short*)(ws + 3 * SZ);
    unsigned short* Wob = (unsigned short*)(ws + 3 * SZ + HSZ);
    // V region [4SZ,5SZ): V fp32 ; later Hb2 bf16 [0,16) + W1b [16,24) + W2b [24,32)
    float* V = (float*)(ws + 4 * SZ);
    unsigned short* Hb2 = (unsigned short*)(ws + 4 * SZ);
    unsigned short* W1b = (unsigned short*)(ws + 4 * SZ + HSZ);
    unsigned short* W2b = (unsigned short*)(ws + 4 * SZ + HSZ + 8 * 1024 * 1024);
    // G bf16 (8192x4096 = 64MB) spans H+QK regions
    unsigned short* G = (unsigned short*)(ws + 2 * SZ);
    char* p = ws + 5 * SZ;
    float* Lg   = (float*)p; p += (size_t)NBH * NHASH * TSEQ * sizeof(float);
    float* invn = (float*)p; p += (size_t)NBH * TSEQ * sizeof(float);
    int*   bucket = (int*)p; p += (size_t)NBH * NHASH * TSEQ * sizeof(int);
    int*   st     = (int*)p; p += (size_t)NBH * NHASH * TSEQ * sizeof(int);

    const int MROWS = BSZ * TSEQ;    // 8192
    const int NELEM = MROWS * DIMM;  // 8388608

    init_kernel<<<(NELEM + 255) / 256, 256, 0, stream>>>(x, X1, X2, NELEM);

    for (int l = 0; l < 2; l++) {
        const float* wqk = Wqk + (size_t)l * DIMM * DIMM;
        const float* wv  = Wv  + (size_t)l * DIMM * DIMM;
        const float* wo  = Wo  + (size_t)l * DIMM * DIMM;
        const float* w1  = W1  + (size_t)l * DIMM * FFD;
        const float* w2  = W2  + (size_t)l * FFD * DIMM;
        const float* rotl = rot + (size_t)l * DH * NHASH * (NBUCK / 2);

        // ---- attention: a = LSHAttn(LN(x2)); y1 = x1 + a ----
        ln_bf16_kernel<<<MROWS, 256, 0, stream>>>(X2, ln1g + l * DIMM, ln1b + l * DIMM, Hb);
        convT_kernel<<<dim3(32, 32), 256, 0, stream>>>(wqk, Wb, DIMM, DIMM);
        mgemm_kernel<0><<<dim3(8, 64), 256, 0, stream>>>(Hb, Wb, nullptr, nullptr, QK,
                                                         MROWS, DIMM, DIMM, 0);
        convT_kernel<<<dim3(32, 32), 256, 0, stream>>>(wv, Wb, DIMM, DIMM);
        mgemm_kernel<0><<<dim3(8, 64), 256, 0, stream>>>(Hb, Wb, nullptr, nullptr, V,
                                                         MROWS, DIMM, DIMM, 0);
        bucket2_kernel<<<dim3(TSEQ / 2, BSZ), 256, 0, stream>>>(
            X2, ln1g + l * DIMM, ln1b + l * DIMM, wqk, rotl, bucket);
        sort_kernel<<<dim3(NHASH, NBH), 64, 0, stream>>>(bucket, st);
        norm_kernel<<<dim3(TSEQ / 4, NBH), 256, 0, stream>>>(QK, invn);
        attn_kernel<0><<<dim3(NCHUNK, NBH), 256, 0, stream>>>(QK, V, invn, st, nullptr, Lg);
        zero_kernel<<<(NELEM + 255) / 256, 256, 0, stream>>>(AO, NELEM);
        attn_kernel<1><<<dim3(NCHUNK, NBH), 256, 0, stream>>>(QK, V, invn, st, Lg, AO);
        c2b_kernel<<<(NELEM + 255) / 256, 256, 0, stream>>>(AO, AOb, NELEM);
        convT_kernel<<<dim3(32, 32), 256, 0, stream>>>(wo, Wob, DIMM, DIMM);
        mgemm_kernel<0><<<dim3(8, 64), 256, 0, stream>>>(AOb, Wob, bo + l * DIMM, X1, X1,
                                                         MROWS, DIMM, DIMM, 1 | 4);

        // ---- feed-forward: y2 = x2 + FF(LN(y1)) ----
        ln_bf16_kernel<<<MROWS, 256, 0, stream>>>(X1, ln2g + l * DIMM, ln2b + l * DIMM, Hb2);
        convT_kernel<<<dim3(128, 32), 256, 0, stream>>>(w1, W1b, DIMM, FFD);
        mgemm_kernel<1><<<dim3(32, 64), 256, 0, stream>>>(Hb2, W1b, b1 + l * FFD, nullptr, G,
                                                          MROWS, FFD, DIMM, 1 | 2);
        convT_kernel<<<dim3(32, 128), 256, 0, stream>>>(w2, W2b, FFD, DIMM);
        mgemm_kernel<0><<<dim3(8, 64), 256, 0, stream>>>(G, W2b, b2 + l * DIMM, X2, X2,
                                                         MROWS, DIMM, FFD, 1 | 4);
    }

    final_kernel<<<(NELEM + 255) / 256, 256, 0, stream>>>(X1, X2, out, NELEM);
}

// Round 7
// 3746.374 us; speedup vs baseline: 3.2754x; 1.1758x over previous
//
#include <hip/hip_runtime.h>
#include <hip/hip_bf16.h>

// ---------------- model constants ----------------
#define TSEQ   4096
#define DIMM   1024
#define NHEADS 8
#define DH     128
#define NHASH  4
#define NBUCK  64
#define NCHUNK 256           // NHASH * NBUCK chunks of 64 sorted positions
#define BSZ    2
#define NBH    16            // BSZ * NHEADS
#define FFD    4096

typedef __attribute__((ext_vector_type(4))) float f32x4;
typedef __attribute__((ext_vector_type(8))) short s16x8;

__device__ __forceinline__ unsigned short f2bf(float f) {
    union { float f; unsigned int u; } x; x.f = f;
    unsigned int r = x.u + 0x7FFFu + ((x.u >> 16) & 1u);   // RNE
    return (unsigned short)(r >> 16);
}

__device__ __forceinline__ void async16(const void* g, void* l) {
    __builtin_amdgcn_global_load_lds(
        (const __attribute__((address_space(1))) unsigned int*)g,
        (__attribute__((address_space(3))) unsigned int*)l, 16, 0, 0);
}

__device__ __forceinline__ float gelu_tanh(float x) {
    float x3 = x * x * x;
    float inner = 0.7978845608028654f * (x + 0.044715f * x3);
    return 0.5f * x * (1.0f + tanhf(inner));
}

// ---------------- init / zero / converts ----------------
__global__ void init_kernel(const float* __restrict__ x, float* __restrict__ X1,
                            float* __restrict__ X2, int n) {
    int i = blockIdx.x * blockDim.x + threadIdx.x;
    if (i < n) { float v = x[i]; X1[i] = v; X2[i] = v; }
}

__global__ void zero_kernel(float* __restrict__ p, int n) {
    int i = blockIdx.x * blockDim.x + threadIdx.x;
    if (i < n) p[i] = 0.f;
}

__global__ void initmw_kernel(float* __restrict__ M, float* __restrict__ W, int n) {
    int i = blockIdx.x * blockDim.x + threadIdx.x;
    if (i < n) { M[i] = -3.0e38f; W[i] = 0.f; }
}

// AOb = bf16(U / Wsum)
__global__ void div_kernel(const float* __restrict__ U, const float* __restrict__ Wst,
                           unsigned short* __restrict__ AOb, int n) {
    int i = blockIdx.x * blockDim.x + threadIdx.x;
    if (i < n) {
        int row = i >> 10, col = i & 1023;
        int b = row >> 12, t = row & 4095, head = col >> 7;
        float w = Wst[(size_t)(b * 8 + head) * TSEQ + t];
        AOb[i] = f2bf(U[i] / w);
    }
}

// convert + transpose: in[K x N] fp32 -> out[N x K] bf16
__global__ __launch_bounds__(256) void convT_kernel(const float* __restrict__ in,
                                                    unsigned short* __restrict__ out,
                                                    int K, int N) {
    __shared__ float tile[32][33];
    int n0 = blockIdx.x * 32, k0 = blockIdx.y * 32;
    int tx = threadIdx.x & 31, ty = threadIdx.x >> 5;
    #pragma unroll
    for (int r = 0; r < 4; r++)
        tile[ty + r * 8][tx] = in[(size_t)(k0 + ty + r * 8) * N + n0 + tx];
    __syncthreads();
    #pragma unroll
    for (int r = 0; r < 4; r++)
        out[(size_t)(n0 + ty + r * 8) * K + k0 + tx] = f2bf(tile[tx][ty + r * 8]);
}

// ---------------- layernorm -> bf16 out ----------------
__global__ __launch_bounds__(256) void ln_bf16_kernel(const float* __restrict__ in,
                                                      const float* __restrict__ g,
                                                      const float* __restrict__ bb,
                                                      unsigned short* __restrict__ out) {
    int row = blockIdx.x;
    int tid = threadIdx.x;
    const float* xr = in + (size_t)row * DIMM;
    float v[4];
    float s = 0.f, sq = 0.f;
    #pragma unroll
    for (int k = 0; k < 4; k++) { float t = xr[tid + 256 * k]; v[k] = t; s += t; sq += t * t; }
    __shared__ float rs[256], rq[256];
    rs[tid] = s; rq[tid] = sq; __syncthreads();
    for (int off = 128; off > 0; off >>= 1) {
        if (tid < off) { rs[tid] += rs[tid + off]; rq[tid] += rq[tid + off]; }
        __syncthreads();
    }
    float mu  = rs[0] * (1.f / DIMM);
    float var = rq[0] * (1.f / DIMM) - mu * mu;
    float rstd = rsqrtf(var + 1e-5f);
    unsigned short* orow = out + (size_t)row * DIMM;
    #pragma unroll
    for (int k = 0; k < 4; k++) {
        int c = tid + 256 * k;
        orow[c] = f2bf((v[k] - mu) * rstd * g[c] + bb[c]);
    }
}

// ---------------- bf16 MFMA GEMM: C = A @ B [+bias][gelu][+resid] ----------------
template<int OUT_BF16>
__global__ __launch_bounds__(256) void mgemm_kernel(const unsigned short* __restrict__ A,
                                                    const unsigned short* __restrict__ Bt,
                                                    const float* __restrict__ bias,
                                                    const float* __restrict__ resid,
                                                    void* __restrict__ Cv,
                                                    int M, int N, int K, int flags) {
    __shared__ __align__(16) unsigned short sA[128 * 32];
    __shared__ __align__(16) unsigned short sB[128 * 32];
    int tid = threadIdx.x;
    int wave = tid >> 6, lane = tid & 63;
    int n0 = blockIdx.x * 128, m0 = blockIdx.y * 128;
    int wr = (wave >> 1) * 64, wc = (wave & 1) * 64;
    f32x4 acc[4][4] = {};
    int c1 = tid, c2 = tid + 256;
    const unsigned short* gA1 = A + (size_t)(m0 + (c1 >> 2)) * K + (c1 & 3) * 8;
    const unsigned short* gA2 = A + (size_t)(m0 + (c2 >> 2)) * K + (c2 & 3) * 8;
    const unsigned short* gB1 = Bt + (size_t)(n0 + (c1 >> 2)) * K + (c1 & 3) * 8;
    const unsigned short* gB2 = Bt + (size_t)(n0 + (c2 >> 2)) * K + (c2 & 3) * 8;
    unsigned short* lA1 = sA + wave * 512;
    unsigned short* lA2 = sA + 2048 + wave * 512;
    unsigned short* lB1 = sB + wave * 512;
    unsigned short* lB2 = sB + 2048 + wave * 512;
    int qk8 = (lane >> 4) * 8;
    int r16 = lane & 15;
    for (int k0 = 0; k0 < K; k0 += 32) {
        __syncthreads();
        async16(gA1 + k0, lA1);
        async16(gA2 + k0, lA2);
        async16(gB1 + k0, lB1);
        async16(gB2 + k0, lB2);
        __syncthreads();
        s16x8 af[4], bf[4];
        #pragma unroll
        for (int i = 0; i < 4; i++) {
            af[i] = *(const s16x8*)&sA[(wr + i * 16 + r16) * 32 + qk8];
            bf[i] = *(const s16x8*)&sB[(wc + i * 16 + r16) * 32 + qk8];
        }
        #pragma unroll
        for (int mi = 0; mi < 4; mi++)
            #pragma unroll
            for (int ni = 0; ni < 4; ni++)
                acc[mi][ni] = __builtin_amdgcn_mfma_f32_16x16x32_bf16(af[mi], bf[ni], acc[mi][ni], 0, 0, 0);
    }
    #pragma unroll
    for (int mi = 0; mi < 4; mi++) {
        #pragma unroll
        for (int r = 0; r < 4; r++) {
            int row = m0 + wr + mi * 16 + (lane >> 4) * 4 + r;
            #pragma unroll
            for (int ni = 0; ni < 4; ni++) {
                int col = n0 + wc + ni * 16 + (lane & 15);
                float v = acc[mi][ni][r];
                if (flags & 1) v += bias[col];
                if (flags & 2) v = gelu_tanh(v);
                if (flags & 4) v += resid[(size_t)row * N + col];
                if (OUT_BF16) ((unsigned short*)Cv)[(size_t)row * N + col] = f2bf(v);
                else          ((float*)Cv)[(size_t)row * N + col] = v;
            }
        }
    }
}

// ---------------- fp64 bucketing v3: 4 tokens/block, float4 col loads ----------------
// Per-output fp64 op order identical to verified r5 chain (serial k, serial d).
__global__ __launch_bounds__(256) void bucket4_kernel(const float* __restrict__ Xsrc,
                                                      const float* __restrict__ g,
                                                      const float* __restrict__ bb,
                                                      const float* __restrict__ Wqk,
                                                      const float* __restrict__ rot,
                                                      int* __restrict__ bucket) {
    int b = blockIdx.y;
    int t0 = blockIdx.x * 4;
    int tid = threadIdx.x;
    __shared__ double h64[4][DIMM];      // 32 KB; reused as rots after GEMM
    __shared__ double qk64[4][DIMM];     // 32 KB
    __shared__ double red[256];

    #pragma unroll
    for (int tt = 0; tt < 4; tt++) {
        const float* xr = Xsrc + (size_t)(b * TSEQ + t0 + tt) * DIMM;
        double s = 0.0, sq = 0.0;
        for (int k = tid; k < DIMM; k += 256) {
            double v = (double)xr[k];
            h64[tt][k] = v; s += v; sq += v * v;
        }
        red[tid] = s; __syncthreads();
        for (int off = 128; off > 0; off >>= 1) { if (tid < off) red[tid] += red[tid + off]; __syncthreads(); }
        double mu = red[0] * (1.0 / DIMM);
        __syncthreads();
        red[tid] = sq; __syncthreads();
        for (int off = 128; off > 0; off >>= 1) { if (tid < off) red[tid] += red[tid + off]; __syncthreads(); }
        double var = red[0] * (1.0 / DIMM) - mu * mu;
        double rstd = 1.0 / sqrt(var + 1e-5);
        __syncthreads();
        for (int k = tid; k < DIMM; k += 256)
            h64[tt][k] = (h64[tt][k] - mu) * rstd * (double)g[k] + (double)bb[k];
        __syncthreads();
    }

    // qk = LN64 @ Wqk : each thread: 4 tokens x 4 consecutive cols
    int c0 = tid * 4;
    double a[4][4] = {};
    for (int k = 0; k < DIMM; k++) {
        f32x4 w4 = *(const f32x4*)&Wqk[(size_t)k * DIMM + c0];
        double w0 = (double)w4.x, w1 = (double)w4.y, w2 = (double)w4.z, w3 = (double)w4.w;
        #pragma unroll
        for (int tt = 0; tt < 4; tt++) {
            double h = h64[tt][k];
            a[tt][0] += h * w0; a[tt][1] += h * w1; a[tt][2] += h * w2; a[tt][3] += h * w3;
        }
    }
    #pragma unroll
    for (int tt = 0; tt < 4; tt++)
        #pragma unroll
        for (int j = 0; j < 4; j++)
            qk64[tt][c0 + j] = a[tt][j];
    __syncthreads();

    // rotation: rotated[j] = sum_d qk64[head(j)*128+d] * rot[d*128 + (j&127)]
    int head = c0 >> 7;          // constant per thread (4 | 128)
    int jj0 = c0 & 127;
    double r[4][4] = {};
    for (int d = 0; d < 128; d++) {
        f32x4 rv4 = *(const f32x4*)&rot[d * 128 + jj0];
        double r0 = (double)rv4.x, r1 = (double)rv4.y, r2 = (double)rv4.z, r3 = (double)rv4.w;
        #pragma unroll
        for (int tt = 0; tt < 4; tt++) {
            double q = qk64[tt][head * 128 + d];
            r[tt][0] += q * r0; r[tt][1] += q * r1; r[tt][2] += q * r2; r[tt][3] += q * r3;
        }
    }
    double* rots = &h64[0][0];
    #pragma unroll
    for (int tt = 0; tt < 4; tt++)
        #pragma unroll
        for (int j = 0; j < 4; j++)
            rots[tt * DIMM + c0 + j] = r[tt][j];
    __syncthreads();

    if (tid < 128) {
        int tt = tid >> 5, idx = tid & 31;
        int hd = idx >> 2, h = idx & 3;
        const double* rr = rots + tt * DIMM + hd * 128 + h * 32;
        double best = -1e300; int bi = 0;
        for (int j = 0; j < 64; j++) {       // first-max wins, matches argmax
            double v = (j < 32) ? rr[j] : -rr[j - 32];
            if (v > best) { best = v; bi = j; }
        }
        bucket[(size_t)((b * 8 + hd) * NHASH + h) * TSEQ + (t0 + tt)] = bi;
    }
}

// ---------------- stable counting sort per (bh, hash round) ----------------
__global__ __launch_bounds__(64) void sort_kernel(const int* __restrict__ bucket,
                                                  int* __restrict__ st) {
    int h = blockIdx.x, bh = blockIdx.y;
    int tid = threadIdx.x;
    __shared__ int sbuck[TSEQ];
    __shared__ int cnt[NBUCK];
    cnt[tid] = 0;
    __syncthreads();
    const int* brow = bucket + (size_t)(bh * NHASH + h) * TSEQ;
    for (int t = tid; t < TSEQ; t += 64) {
        int bu = brow[t];
        sbuck[t] = bu;
        atomicAdd(&cnt[bu], 1);
    }
    __syncthreads();
    if (tid == 0) {
        int run = 0;
        for (int i = 0; i < NBUCK; i++) { int c = cnt[i]; cnt[i] = run; run += c; }
    }
    __syncthreads();
    int off = cnt[tid];
    int* strow = st + (size_t)bh * (NHASH * TSEQ) + h * TSEQ;
    for (int t = 0; t < TSEQ; t++) {
        if (sbuck[t] == tid) strow[off++] = t;
    }
}

// ---------------- per-token key inverse norms ----------------
__global__ __launch_bounds__(256) void norm_kernel(const float* __restrict__ QK,
                                                   float* __restrict__ invn) {
    int bh = blockIdx.y;
    int b = bh >> 3, head = bh & 7;
    int wave = threadIdx.x >> 6, lane = threadIdx.x & 63;
    int t = blockIdx.x * 4 + wave;
    const float* row = QK + (size_t)(b * TSEQ + t) * DIMM + head * DH;
    float v0 = row[lane], v1 = row[lane + 64];
    float s = v0 * v0 + v1 * v1;
    #pragma unroll
    for (int off = 32; off > 0; off >>= 1) s += __shfl_xor(s, off, 64);
    if (lane == 0) invn[bh * TSEQ + t] = rsqrtf(s + 1e-12f);
}

// ---------------- chunked LSH attention, single pass, online cross-round combine ----
// Launched once per round r (sequential). Each token appears in exactly one chunk
// per round -> race-free RMW of (Mst, Wst, U).
__global__ __launch_bounds__(256) void attn_online_kernel(const float* __restrict__ QK,
                                                          const float* __restrict__ V,
                                                          const float* __restrict__ invn,
                                                          const int* __restrict__ st,
                                                          float* __restrict__ Mst,
                                                          float* __restrict__ Wst,
                                                          float* __restrict__ U,
                                                          int roundBase) {
    int c  = roundBase + blockIdx.x;   // global chunk id
    int bh = blockIdx.y;
    int b = bh >> 3, head = bh & 7;
    const float* QKb = QK + (size_t)b * TSEQ * DIMM + head * DH;
    const float* Vb  = V  + (size_t)b * TSEQ * DIMM + head * DH;
    const int* stb = st + (size_t)bh * (NHASH * TSEQ);
    int prev = (c + NCHUNK - 1) & (NCHUNK - 1);
    int tid = threadIdx.x;
    int tx = tid & 15, ty = tid >> 4;

    __shared__ float sdots[64][129];
    __shared__ float sstage[3264];
    __shared__ int   sbt[64];
    __shared__ int   sbkt[128];
    __shared__ float sinv[128];
    __shared__ float sa[64], sb[64];

    if (tid < 64) sbt[tid] = stb[c * 64 + tid];
    if (tid < 128) {
        int j = tid;
        int p = (j < 64) ? (c * 64 + j) : (prev * 64 + j - 64);
        int tk = stb[p];
        sbkt[j] = tk;
        sinv[j] = invn[bh * TSEQ + tk];
    }
    __syncthreads();

    // ---- dots = bq @ bk^T ----
    float acc[4][8] = {};
    float* sQ = sstage;
    float* sK = sstage + 64 * 17;
    for (int d0 = 0; d0 < DH; d0 += 16) {
        #pragma unroll
        for (int q = 0; q < 4; q++) {
            int idx = q * 256 + tid;
            int i = idx >> 4, dd = idx & 15;
            sQ[i * 17 + dd] = QKb[(size_t)sbt[i] * DIMM + d0 + dd];
        }
        #pragma unroll
        for (int q = 0; q < 8; q++) {
            int idx = q * 256 + tid;
            int j = idx >> 4, dd = idx & 15;
            sK[j * 17 + dd] = QKb[(size_t)sbkt[j] * DIMM + d0 + dd];
        }
        __syncthreads();
        #pragma unroll
        for (int dd = 0; dd < 16; dd++) {
            float a[4], bv[8];
            #pragma unroll
            for (int ri = 0; ri < 4; ri++) a[ri] = sQ[(ty * 4 + ri) * 17 + dd];
            #pragma unroll
            for (int ci = 0; ci < 8; ci++) bv[ci] = sK[(tx + 16 * ci) * 17 + dd];
            #pragma unroll
            for (int ri = 0; ri < 4; ri++)
                #pragma unroll
                for (int ci = 0; ci < 8; ci++)
                    acc[ri][ci] += a[ri] * bv[ci];
        }
        __syncthreads();
    }
    const float scale = 0.08838834764831845f;
    #pragma unroll
    for (int ri = 0; ri < 4; ri++) {
        int i = ty * 4 + ri;
        #pragma unroll
        for (int ci = 0; ci < 8; ci++) {
            int j = tx + 16 * ci;
            float v = acc[ri][ci] * sinv[j] * scale;
            if (sbt[i] == sbkt[j]) v -= 1e5f;
            sdots[i][j] = v;
        }
    }
    __syncthreads();

    // ---- row softmax + online merge factors ----
    if (tid < 64) {
        float m = -3.402823466e38f;
        for (int j = 0; j < 128; j++) m = fmaxf(m, sdots[tid][j]);
        float s = 0.f;
        for (int j = 0; j < 128; j++) s += expf(sdots[tid][j] - m);
        float inv = 1.f / s;
        for (int j = 0; j < 128; j++) sdots[tid][j] = expf(sdots[tid][j] - m) * inv;
        float lse = m + logf(s);
        int tok = sbt[tid];
        size_t mi = (size_t)bh * TSEQ + tok;
        float oldM = Mst[mi], oldW = Wst[mi];
        float newM = fmaxf(oldM, lse);
        float af = expf(oldM - newM);
        float bf = expf(lse - newM);
        Mst[mi] = newM;
        Wst[mi] = oldW * af + bf;
        sa[tid] = af; sb[tid] = bf;
    }
    __syncthreads();

    // ---- PV then U update: U = U*a + (P@V)*b ----
    float acc2[4][8] = {};
    float* sV = sstage;
    for (int j0 = 0; j0 < 128; j0 += 16) {
        #pragma unroll
        for (int q = 0; q < 8; q++) {
            int idx = q * 256 + tid;
            int jj = idx >> 7, d = idx & 127;
            sV[jj * 129 + d] = Vb[(size_t)sbkt[j0 + jj] * DIMM + d];
        }
        __syncthreads();
        #pragma unroll
        for (int jj = 0; jj < 16; jj++) {
            float a[4], vv[8];
            #pragma unroll
            for (int ri = 0; ri < 4; ri++) a[ri] = sdots[ty * 4 + ri][j0 + jj];
            #pragma unroll
            for (int ci = 0; ci < 8; ci++) vv[ci] = sV[jj * 129 + tx + 16 * ci];
            #pragma unroll
            for (int ri = 0; ri < 4; ri++)
                #pragma unroll
                for (int ci = 0; ci < 8; ci++)
                    acc2[ri][ci] += a[ri] * vv[ci];
        }
        __syncthreads();
    }
    #pragma unroll
    for (int ri = 0; ri < 4; ri++) {
        int i = ty * 4 + ri;
        float af = sa[i], bf = sb[i];
        float* urow = U + (size_t)(b * TSEQ + sbt[i]) * DIMM + head * DH;
        #pragma unroll
        for (int ci = 0; ci < 8; ci++) {
            int d = tx + 16 * ci;
            urow[d] = urow[d] * af + acc2[ri][ci] * bf;
        }
    }
}

// ---------------- final: out = 0.5*(X1+X2), fp32 ----------------
__global__ void final_kernel(const float* __restrict__ X1, const float* __restrict__ X2,
                             float* __restrict__ out, int n) {
    int i = blockIdx.x * blockDim.x + threadIdx.x;
    if (i < n) out[i] = 0.5f * (X1[i] + X2[i]);
}

extern "C" void kernel_launch(void* const* d_in, const int* in_sizes, int n_in,
                              void* d_out, int out_size, void* d_ws, size_t ws_size,
                              hipStream_t stream) {
    (void)in_sizes; (void)n_in; (void)out_size; (void)ws_size;
    const float* x    = (const float*)d_in[0];
    const float* ln1g = (const float*)d_in[2];
    const float* ln1b = (const float*)d_in[3];
    const float* Wqk  = (const float*)d_in[4];
    const float* Wv   = (const float*)d_in[5];
    const float* Wo   = (const float*)d_in[6];
    const float* bo   = (const float*)d_in[7];
    const float* ln2g = (const float*)d_in[8];
    const float* ln2b = (const float*)d_in[9];
    const float* W1   = (const float*)d_in[10];
    const float* b1   = (const float*)d_in[11];
    const float* W2   = (const float*)d_in[12];
    const float* b2   = (const float*)d_in[13];
    const float* rot  = (const float*)d_in[14];
    float* out = (float*)d_out;

    // ---- workspace layout (163.1 MB, same known-good footprint) ----
    char* ws = (char*)d_ws;
    const size_t SZ  = (size_t)BSZ * TSEQ * DIMM * sizeof(float);   // 32 MB
    const size_t HSZ = SZ / 2;                                      // 16 MB
    float* X1 = (float*)(ws + 0 * SZ);
    float* X2 = (float*)(ws + 1 * SZ);
    unsigned short* Hb  = (unsigned short*)(ws + 2 * SZ);           // LN out bf16
    unsigned short* Wb  = (unsigned short*)(ws + 2 * SZ + HSZ);     // weight bf16
    float* AO = (float*)(ws + 2 * SZ);                              // U accumulator fp32
    float* QK = (float*)(ws + 3 * SZ);
    unsigned short* AOb = (unsigned short*)(ws + 3 * SZ);
    unsigned short* Wob = (unsigned short*)(ws + 3 * SZ + HSZ);
    float* V = (float*)(ws + 4 * SZ);
    unsigned short* Hb2 = (unsigned short*)(ws + 4 * SZ);
    unsigned short* W1b = (unsigned short*)(ws + 4 * SZ + HSZ);
    unsigned short* W2b = (unsigned short*)(ws + 4 * SZ + HSZ + 8 * 1024 * 1024);
    unsigned short* G = (unsigned short*)(ws + 2 * SZ);             // FF hidden bf16 64MB
    char* p = ws + 5 * SZ;
    float* Mst  = (float*)p; p += (size_t)NBH * TSEQ * sizeof(float);   // 256 KB
    float* Wst  = (float*)p; p += (size_t)NBH * TSEQ * sizeof(float);   // 256 KB
    float* invn = (float*)p; p += (size_t)NBH * TSEQ * sizeof(float);   // 256 KB
    int*   bucket = (int*)p; p += (size_t)NBH * NHASH * TSEQ * sizeof(int);
    int*   st     = (int*)p; p += (size_t)NBH * NHASH * TSEQ * sizeof(int);

    const int MROWS = BSZ * TSEQ;    // 8192
    const int NELEM = MROWS * DIMM;  // 8388608
    const int NMW = NBH * TSEQ;      // 65536

    init_kernel<<<(NELEM + 255) / 256, 256, 0, stream>>>(x, X1, X2, NELEM);

    for (int l = 0; l < 2; l++) {
        const float* wqk = Wqk + (size_t)l * DIMM * DIMM;
        const float* wv  = Wv  + (size_t)l * DIMM * DIMM;
        const float* wo  = Wo  + (size_t)l * DIMM * DIMM;
        const float* w1  = W1  + (size_t)l * DIMM * FFD;
        const float* w2  = W2  + (size_t)l * FFD * DIMM;
        const float* rotl = rot + (size_t)l * DH * NHASH * (NBUCK / 2);

        // ---- attention: a = LSHAttn(LN(x2)); y1 = x1 + a ----
        ln_bf16_kernel<<<MROWS, 256, 0, stream>>>(X2, ln1g + l * DIMM, ln1b + l * DIMM, Hb);
        convT_kernel<<<dim3(32, 32), 256, 0, stream>>>(wqk, Wb, DIMM, DIMM);
        mgemm_kernel<0><<<dim3(8, 64), 256, 0, stream>>>(Hb, Wb, nullptr, nullptr, QK,
                                                         MROWS, DIMM, DIMM, 0);
        convT_kernel<<<dim3(32, 32), 256, 0, stream>>>(wv, Wb, DIMM, DIMM);
        mgemm_kernel<0><<<dim3(8, 64), 256, 0, stream>>>(Hb, Wb, nullptr, nullptr, V,
                                                         MROWS, DIMM, DIMM, 0);
        bucket4_kernel<<<dim3(TSEQ / 4, BSZ), 256, 0, stream>>>(
            X2, ln1g + l * DIMM, ln1b + l * DIMM, wqk, rotl, bucket);
        sort_kernel<<<dim3(NHASH, NBH), 64, 0, stream>>>(bucket, st);
        norm_kernel<<<dim3(TSEQ / 4, NBH), 256, 0, stream>>>(QK, invn);
        initmw_kernel<<<(NMW + 255) / 256, 256, 0, stream>>>(Mst, Wst, NMW);
        zero_kernel<<<(NELEM + 255) / 256, 256, 0, stream>>>(AO, NELEM);
        for (int r = 0; r < NHASH; r++)
            attn_online_kernel<<<dim3(NBUCK, NBH), 256, 0, stream>>>(
                QK, V, invn, st, Mst, Wst, AO, r * NBUCK);
        div_kernel<<<(NELEM + 255) / 256, 256, 0, stream>>>(AO, Wst, AOb, NELEM);
        convT_kernel<<<dim3(32, 32), 256, 0, stream>>>(wo, Wob, DIMM, DIMM);
        mgemm_kernel<0><<<dim3(8, 64), 256, 0, stream>>>(AOb, Wob, bo + l * DIMM, X1, X1,
                                                         MROWS, DIMM, DIMM, 1 | 4);

        // ---- feed-forward: y2 = x2 + FF(LN(y1)) ----
        ln_bf16_kernel<<<MROWS, 256, 0, stream>>>(X1, ln2g + l * DIMM, ln2b + l * DIMM, Hb2);
        convT_kernel<<<dim3(128, 32), 256, 0, stream>>>(w1, W1b, DIMM, FFD);
        mgemm_kernel<1><<<dim3(32, 64), 256, 0, stream>>>(Hb2, W1b, b1 + l * FFD, nullptr, G,
                                                          MROWS, FFD, DIMM, 1 | 2);
        convT_kernel<<<dim3(32, 128), 256, 0, stream>>>(w2, W2b, FFD, DIMM);
        mgemm_kernel<0><<<dim3(8, 64), 256, 0, stream>>>(G, W2b, b2 + l * DIMM, X2, X2,
                                                         MROWS, DIMM, FFD, 1 | 4);
    }

    final_kernel<<<(NELEM + 255) / 256, 256, 0, stream>>>(X1, X2, out, NELEM);
}